// Round 1
// baseline (253.926 us; speedup 1.0000x reference)
//
#include <hip/hip_runtime.h>
#include <hip/hip_bf16.h>
#include <math.h>

#define L 2048
#define NB 16
#define ROWS_PER_BLOCK 16
#define THREADS 256
#define GAF_EPS 1e-8f

// gaf[b,i,j] = cos(phi_i + phi_j) = c_i*c_j - s_i*s_j
// with c = clip(2*(x-min)/(max-min+eps) - 1), s = sqrt(1 - c^2).
// Write-bandwidth bound: 256 MiB of output at ~6.3 TB/s -> ~43 us floor.
__global__ __launch_bounds__(THREADS) void gaf_kernel(const float* __restrict__ x,
                                                      float* __restrict__ out) {
    __shared__ float sc[L];   // c_j per column of this batch
    __shared__ float ss[L];   // s_j per column
    __shared__ float red[8];  // 4 waves: min in [0..3], max in [4..7]

    const int chunks_per_batch = L / ROWS_PER_BLOCK;           // 128
    const int b = blockIdx.x / chunks_per_batch;
    const int i0 = (blockIdx.x % chunks_per_batch) * ROWS_PER_BLOCK;
    const int t = threadIdx.x;
    const float* __restrict__ xrow = x + (size_t)b * L;

    // --- load 8 elements/thread (coalesced, stride THREADS), track min/max ---
    float v[8];
    float mn = INFINITY, mx = -INFINITY;
#pragma unroll
    for (int k = 0; k < 8; ++k) {
        v[k] = xrow[t + k * THREADS];
        mn = fminf(mn, v[k]);
        mx = fmaxf(mx, v[k]);
    }
    // wave-level butterfly (64 lanes)
#pragma unroll
    for (int off = 32; off > 0; off >>= 1) {
        mn = fminf(mn, __shfl_down(mn, off));
        mx = fmaxf(mx, __shfl_down(mx, off));
    }
    const int wave = t >> 6;
    if ((t & 63) == 0) { red[wave] = mn; red[4 + wave] = mx; }
    __syncthreads();
    if (t == 0) {
        red[0] = fminf(fminf(red[0], red[1]), fminf(red[2], red[3]));
        red[4] = fmaxf(fmaxf(red[4], red[5]), fmaxf(red[6], red[7]));
    }
    __syncthreads();
    mn = red[0];
    mx = red[4];
    const float inv = 1.0f / (mx - mn + GAF_EPS);

    // --- compute c, s into LDS ---
#pragma unroll
    for (int k = 0; k < 8; ++k) {
        float c = 2.0f * ((v[k] - mn) * inv) - 1.0f;
        c = fminf(fmaxf(c, -1.0f + GAF_EPS), 1.0f - GAF_EPS);
        const int idx = t + k * THREADS;
        sc[idx] = c;
        ss[idx] = sqrtf(fmaxf(1.0f - c * c, 0.0f));
    }
    __syncthreads();

    // --- stream 16 output rows, float4 coalesced stores ---
    float* __restrict__ obase = out + ((size_t)b * L + (size_t)i0) * L;
#pragma unroll
    for (int i = 0; i < ROWS_PER_BLOCK; ++i) {
        const float ci = sc[i0 + i];   // same-address LDS broadcast: free
        const float si = ss[i0 + i];
        float4* __restrict__ orow = (float4*)(obase + (size_t)i * L);
#pragma unroll
        for (int it = 0; it < L / (4 * THREADS); ++it) {  // 2 iterations
            const int j4 = t + it * THREADS;
            const float4 cj = ((const float4*)sc)[j4];
            const float4 sj = ((const float4*)ss)[j4];
            float4 o;
            o.x = ci * cj.x - si * sj.x;
            o.y = ci * cj.y - si * sj.y;
            o.z = ci * cj.z - si * sj.z;
            o.w = ci * cj.w - si * sj.w;
            orow[j4] = o;
        }
    }
}

extern "C" void kernel_launch(void* const* d_in, const int* in_sizes, int n_in,
                              void* d_out, int out_size, void* d_ws, size_t ws_size,
                              hipStream_t stream) {
    const float* x = (const float*)d_in[0];
    float* out = (float*)d_out;
    const dim3 grid(NB * (L / ROWS_PER_BLOCK));  // 16 * 128 = 2048 blocks
    gaf_kernel<<<grid, THREADS, 0, stream>>>(x, out);
}